// Round 3
// baseline (162.528 us; speedup 1.0000x reference)
//
#include <hip/hip_runtime.h>
#include <stdint.h>

#define NROWS 65536
#define DIM   256
#define NC    1024
#define NO    64

#define BN    128          // rows per block
#define WROWS 32           // rows per wave
#define BC    64           // centers per tile
#define NTILE (NC / BC)    // 16

using bf16x8 = __bf16 __attribute__((ext_vector_type(8)));
using f32x4  = float __attribute__((ext_vector_type(4)));
using u16x4  = unsigned short __attribute__((ext_vector_type(4)));
using u32x2  = unsigned int __attribute__((ext_vector_type(2)));

#define MFMA16(a, b, c) __builtin_amdgcn_mfma_f32_16x16x32_bf16((a), (b), (c), 0, 0, 0)

__device__ inline unsigned short bf16_bits(float f) {
    __bf16 h = (__bf16)f;   // RNE
    return __builtin_bit_cast(unsigned short, h);
}

// ---------------- prep kernels ----------------

// centers [C,256] f32 -> bf16, stored with per-row 16B-chunk XOR swizzle
// (chunk_byte ^= (c&7)<<4) so the main kernel's linear global_load_lds
// lands a swizzled LDS tile (m173 pattern). Also c_sq and alpha=1/(2s^2+eps).
__global__ __launch_bounds__(256) void prep_cent(const float* __restrict__ cent,
                                                 const float* __restrict__ sigma,
                                                 unsigned short* __restrict__ cbf,
                                                 float* __restrict__ csq,
                                                 float* __restrict__ alpha) {
    const int wid = threadIdx.x >> 6, lane = threadIdx.x & 63;
    const int c = blockIdx.x * 4 + wid;
    float4 v = ((const float4*)cent)[(size_t)c * 64 + lane];
    u16x4 o;
    o[0] = bf16_bits(v.x); o[1] = bf16_bits(v.y);
    o[2] = bf16_bits(v.z); o[3] = bf16_bits(v.w);
    // lane covers k = lane*4..lane*4+3 -> 16B chunk j = lane>>1, sub-half (lane&1)*8
    int byteoff = c * 512 + (((lane >> 1) * 16) ^ ((c & 7) << 4)) + (lane & 1) * 8;
    *(u16x4*)((char*)cbf + byteoff) = o;
    float ss = v.x * v.x + v.y * v.y + v.z * v.z + v.w * v.w;
    #pragma unroll
    for (int off = 32; off; off >>= 1) ss += __shfl_down(ss, off);
    if (lane == 0) {
        csq[c] = ss;
        float s = sigma[c];
        alpha[c] = 1.0f / (2.0f * s * s + 1e-8f);
    }
}

// W [64,1024] f32 -> bf16 (row o contiguous in c => B-frag reads are 16B).
__global__ __launch_bounds__(256) void prep_w(const float* __restrict__ w,
                                              unsigned short* __restrict__ wbf) {
    const int o = blockIdx.x;
    float4 v = ((const float4*)w)[(size_t)o * 256 + threadIdx.x];
    u16x4 u;
    u[0] = bf16_bits(v.x); u[1] = bf16_bits(v.y);
    u[2] = bf16_bits(v.z); u[3] = bf16_bits(v.w);
    *(u16x4*)(wbf + (size_t)o * NC + threadIdx.x * 4) = u;
}

// ---------------- main fused kernel ----------------
// grid 512, block 256 (4 waves). Wave owns 32 rows. Loop 16 C-tiles of 64.
__global__ __launch_bounds__(256, 2) void rbf_main(
    const float* __restrict__ x,
    const __bf16* __restrict__ cbf, const float* __restrict__ csq,
    const float* __restrict__ alpha, const __bf16* __restrict__ wbf,
    const float* __restrict__ bias, float* __restrict__ out) {

    __shared__ __bf16 cent_lds[BC * DIM];      // 32KB, swizzled rows
    __shared__ __bf16 rbf_lds[4][WROWS * BC];  // 4KB per wave, swizzled

    const int tid  = threadIdx.x;
    const int wid  = tid >> 6;
    const int lane = tid & 63;
    const int l15  = lane & 15;
    const int hi   = lane >> 4;          // 0..3

    const int rowbase = blockIdx.x * BN + wid * WROWS;

    // ---- x fragments straight from f32 global; xsq in-register ----
    // xf[nf][ks]: row = rowbase + nf*16 + l15, k = ks*32 + hi*8 .. +8
    bf16x8 xf[2][8];
    float xsqv[2];
    #pragma unroll
    for (int nf = 0; nf < 2; ++nf) {
        const float* xr = x + (size_t)(rowbase + nf * 16 + l15) * DIM;
        float ss = 0.f;
        #pragma unroll
        for (int ks = 0; ks < 8; ++ks) {
            float4 a = *(const float4*)(xr + ks * 32 + hi * 8);
            float4 b = *(const float4*)(xr + ks * 32 + hi * 8 + 4);
            bf16x8 f;
            f[0] = (__bf16)a.x; f[1] = (__bf16)a.y; f[2] = (__bf16)a.z; f[3] = (__bf16)a.w;
            f[4] = (__bf16)b.x; f[5] = (__bf16)b.y; f[6] = (__bf16)b.z; f[7] = (__bf16)b.w;
            xf[nf][ks] = f;
            ss += a.x * a.x + a.y * a.y + a.z * a.z + a.w * a.w;
            ss += b.x * b.x + b.y * b.y + b.z * b.z + b.w * b.w;
        }
        // lanes sharing l15 (hi=0..3) hold disjoint 64-elem k-slices of the same row
        ss += __shfl_xor(ss, 16);
        ss += __shfl_xor(ss, 32);
        xsqv[nf] = ss;
    }

    float bo[4];
    #pragma unroll
    for (int of = 0; of < 4; ++of) bo[of] = bias[of * 16 + l15];

    f32x4 oacc[2][4];
    #pragma unroll
    for (int nf = 0; nf < 2; ++nf)
        #pragma unroll
        for (int of = 0; of < 4; ++of) {
            f32x4 z = {0.f, 0.f, 0.f, 0.f};
            oacc[nf][of] = z;
        }

    for (int t = 0; t < NTILE; ++t) {
        __syncthreads();  // previous tile's cent_lds reads done
        {   // stage centers tile (32KB) via global_load_lds width=16, linear dest
            const __bf16* src = cbf + (size_t)t * BC * DIM;
            #pragma unroll
            for (int i = 0; i < 8; ++i) {
                const __bf16* g = src + (size_t)(i * 256 + tid) * 8;         // per-lane global
                __bf16* l = (__bf16*)cent_lds + (i * 256 + (wid * 64)) * 8;  // wave-uniform base
                __builtin_amdgcn_global_load_lds(
                    (const __attribute__((address_space(1))) uint32_t*)g,
                    (__attribute__((address_space(3))) uint32_t*)l, 16, 0, 0);
            }
        }
        asm volatile("s_waitcnt vmcnt(0)" ::: "memory");
        __syncthreads();

        // ---- GEMM1 (swapped): S^T[64c][32n] = centers_tile . x^T ----
        f32x4 st[4][2];
        #pragma unroll
        for (int c4 = 0; c4 < 4; ++c4)
            #pragma unroll
            for (int nf = 0; nf < 2; ++nf) {
                f32x4 z = {0.f, 0.f, 0.f, 0.f};
                st[c4][nf] = z;
            }
        #pragma unroll
        for (int ks = 0; ks < 8; ++ks) {
            bf16x8 cf[4];
            #pragma unroll
            for (int c4 = 0; c4 < 4; ++c4) {
                const int crow = c4 * 16 + l15;
                const int byte = crow * 512 + ((ks * 64 + hi * 16) ^ ((crow & 7) << 4));
                cf[c4] = *(const bf16x8*)((const char*)cent_lds + byte);
            }
            #pragma unroll
            for (int c4 = 0; c4 < 4; ++c4)
                #pragma unroll
                for (int nf = 0; nf < 2; ++nf)
                    st[c4][nf] = MFMA16(cf[c4], xf[nf][ks], st[c4][nf]);
        }

        // ---- rbf = exp(-(xsq - 2S + csq)*alpha), pack bf16, stage per-wave ----
        char* const rbase = (char*)&rbf_lds[wid][0];
        #pragma unroll
        for (int c4 = 0; c4 < 4; ++c4) {
            const int cl0 = c4 * 16 + hi * 4;      // c_local of reg r=0
            const int cg  = t * BC + cl0;
            const f32x4 cs4 = *(const f32x4*)(csq + cg);
            const f32x4 al4 = *(const f32x4*)(alpha + cg);
            #pragma unroll
            for (int nf = 0; nf < 2; ++nf) {
                const f32x4 v = st[c4][nf];
                float p0 = __expf((2.0f * v[0] - xsqv[nf] - cs4[0]) * al4[0]);
                float p1 = __expf((2.0f * v[1] - xsqv[nf] - cs4[1]) * al4[1]);
                float p2 = __expf((2.0f * v[2] - xsqv[nf] - cs4[2]) * al4[2]);
                float p3 = __expf((2.0f * v[3] - xsqv[nf] - cs4[3]) * al4[3]);
                u32x2 wv;
                wv[0] = (unsigned)bf16_bits(p0) | ((unsigned)bf16_bits(p1) << 16);
                wv[1] = (unsigned)bf16_bits(p2) | ((unsigned)bf16_bits(p3) << 16);
                const int n = nf * 16 + l15;
                // base is 8B-aligned (bit3 = hi&1 only); XOR touches bits 4-6 only,
                // so one 8B write stays within its swizzled 16B slot
                const int byte = (n * 128 + cl0 * 2) ^ ((n & 7) << 4);
                *(u32x2*)(rbase + byte) = wv;
            }
        }

        // ---- GEMM2: out[32n][64o] += rbf[32n][64c] . Wt[64c][64o] ----
        #pragma unroll
        for (int cs = 0; cs < 2; ++cs) {
            bf16x8 pa[2];
            #pragma unroll
            for (int nf = 0; nf < 2; ++nf) {
                const int n = nf * 16 + l15;
                const int byte = (n * 128 + cs * 64 + hi * 16) ^ ((n & 7) << 4);
                pa[nf] = *(const bf16x8*)((const char*)rbase + byte);
            }
            #pragma unroll
            for (int of = 0; of < 4; ++of) {
                const bf16x8 wb = *(const bf16x8*)(wbf + (size_t)(of * 16 + l15) * NC
                                                   + t * BC + cs * 32 + hi * 8);
                #pragma unroll
                for (int nf = 0; nf < 2; ++nf)
                    oacc[nf][of] = MFMA16(pa[nf], wb, oacc[nf][of]);
            }
        }
    }

    // epilogue: D layout row = hi*4 + r (n), col = l15 (o)
    #pragma unroll
    for (int nf = 0; nf < 2; ++nf)
        #pragma unroll
        for (int of = 0; of < 4; ++of)
            #pragma unroll
            for (int r = 0; r < 4; ++r) {
                const int n = rowbase + nf * 16 + hi * 4 + r;
                out[(size_t)n * NO + of * 16 + l15] = oacc[nf][of][r] + bo[of];
            }
}

// ---------------- launcher ----------------
extern "C" void kernel_launch(void* const* d_in, const int* in_sizes, int n_in,
                              void* d_out, int out_size, void* d_ws, size_t ws_size,
                              hipStream_t stream) {
    const float* x     = (const float*)d_in[0];
    const float* cent  = (const float*)d_in[1];
    const float* sigma = (const float*)d_in[2];
    const float* W     = (const float*)d_in[3];
    const float* b     = (const float*)d_in[4];
    float* out = (float*)d_out;

    char* ws = (char*)d_ws;
    unsigned short* cbf  = (unsigned short*)(ws + 0);        //   524,288 B
    float*          csqp = (float*)(ws + 524288);            //     4,096 B
    float*          alp  = (float*)(ws + 528384);            //     4,096 B
    unsigned short* wbf  = (unsigned short*)(ws + 532480);   //   131,072 B

    prep_cent<<<NC / 4, 256, 0, stream>>>(cent, sigma, cbf, csqp, alp);
    prep_w<<<NO, 256, 0, stream>>>(W, wbf);
    rbf_main<<<NROWS / BN, 256, 0, stream>>>(
        x, (const __bf16*)cbf, csqp, alp, (const __bf16*)wbf, b, out);
}